// Round 13
// baseline (89.948 us; speedup 1.0000x reference)
//
#include <hip/hip_runtime.h>

// fuzzyConv: B=32, H=W=256, C=32, R=8, O=16, 3x3 VALID -> H'=W'=254
// Premise as implicit GEMM on matrix cores (fp16 features, fp32 accum),
// OPERAND-SWAPPED: D1[rule,pixel] = W·X so the epilogue needs no transpose.
//   exponent_r(p) = sum_{tap,c} [ (s2*mu)*x + (-0.5*s2)*x^2 ] + K_r
// TH=10 tile (12 staged rows, 50688 B LDS -> 3 blocks/CU): vertical read
// redundancy 1.29->1.20 (demand-bound hypothesis test). Chunked XCD swizzle.
// Single stage + ONE barrier (R8/R11 template; all pipelined variants were
// neutral or worse). cvt_pkrtz packing, in-register epilogue (exp, shfl
// denom, second MFMA out=cb^T·phi_aug), NT stores.

#define CIN 32
#define HH  256
#define WW  256
#define HO  254
#define WO  254
#define BB  32
#define OO  16

#define TW 64
#define TH 10
#define LROWS 12                    // TH+2 staged input rows
#define LPIX 66                     // TW+2 staged pixels per row
#define ROWCH (LPIX * 4)            // 264 16-B chunks per row (8 fp16 ch each)
#define LDS_CHUNKS (LROWS * ROWCH)  // 3168 chunks = 50688 B
#define STAGE_ITERS 13              // ceil(3168/256)
#define NBAND 26                    // ceil(254/10)
#define NTILE (4 * NBAND * BB)      // 3328 = 8 * 416
#define CPX (NTILE / 8)             // 416 tiles per XCD chunk

typedef _Float16 half8 __attribute__((ext_vector_type(8)));   // 8 fp16 (4 VGPR)
typedef float f32x4 __attribute__((ext_vector_type(4)));

static __device__ __forceinline__ unsigned short f2h(float f) {
    _Float16 h = (_Float16)f;
    return *reinterpret_cast<unsigned short*>(&h);
}

static __device__ __forceinline__ half8 pack_pkrtz(const float4& a, const float4& b) {
    uint4 u;
    u.x = __builtin_bit_cast(unsigned, __builtin_amdgcn_cvt_pkrtz(a.x, a.y));
    u.y = __builtin_bit_cast(unsigned, __builtin_amdgcn_cvt_pkrtz(a.z, a.w));
    u.z = __builtin_bit_cast(unsigned, __builtin_amdgcn_cvt_pkrtz(b.x, b.y));
    u.w = __builtin_bit_cast(unsigned, __builtin_amdgcn_cvt_pkrtz(b.z, b.w));
    return __builtin_bit_cast(half8, u);
}

// ---------------- prep: W-fragments (fp16) + K constants ----------------
// wb: 18 frags = tap(9) x ftype(2); ftype0 pairs with x (w = s2*mu),
// ftype1 pairs with x^2 (w = -0.5*s2). A-operand layout: lane l -> row
// m=l&15 = rule (0-pad >=8), k-element e -> channel c = (l>>4)*8+e.
__global__ __launch_bounds__(256) void prep_kernel(const float* __restrict__ sigma,
                                                   const float* __restrict__ mu,
                                                   unsigned short* __restrict__ wb,
                                                   float* __restrict__ Kc) {
    const int tid = threadIdx.x;
    for (int item = tid; item < 18 * 64; item += 256) {
        const int frag = item >> 6;          // 0..17
        const int lane = item & 63;
        const int tap = frag >> 1, ftype = frag & 1;
        const int n = lane & 15, g = lane >> 4;
#pragma unroll
        for (int e = 0; e < 8; ++e) {
            float wgt = 0.f;
            if (n < 8) {
                const int c = g * 8 + e;
                const float sg = sigma[(tap * CIN + c) * 8 + n];   // (3,3,C,R)
                const float s2 = sg * sg;
                wgt = ftype ? -0.5f * s2 : s2 * mu[n * CIN + c];
            }
            wb[item * 8 + e] = f2h(wgt);
        }
    }
    if (tid < 8) {
        const int r = tid;
        float k = 0.f;
        for (int item = 0; item < 9 * CIN; ++item) {
            const int c = item & 31;
            const float sg = sigma[item * 8 + r];
            const float m = mu[r * CIN + c];
            k = fmaf(sg * sg, m * m, k);
        }
        Kc[r] = -0.5f * k;
    }
}

// ---------------- main kernel ----------------
// Block 256 = 4 waves. Wave w -> output rows i0+w, i0+4+w; waves 0,1 also
// rows i0+8, i0+9. 64 px = 4 N-tiles of 16. LDS: 12 rows x 66 px x 32ch
// fp16, chunk-swizzled (g ^ (px&3)).
__global__ __launch_bounds__(256, 3) void fuzzy_main(const float* __restrict__ x,
                                                     const unsigned short* __restrict__ wb,
                                                     const float* __restrict__ Kc,
                                                     const float* __restrict__ residual,
                                                     const float* __restrict__ cb,
                                                     float* __restrict__ out) {
    __shared__ __align__(16) unsigned char ldsRaw[LDS_CHUNKS * 16];   // 50688 B
    half8* ldsH = reinterpret_cast<half8*>(ldsRaw);

    const int tid = threadIdx.x;
    // chunked XCD swizzle: XCD k gets tiles [k*CPX, (k+1)*CPX) ordered
    // (b, it, jt)-major -> vertical halo neighbors on the same XCD L2.
    const int lin  = blockIdx.x;
    const int tile = (lin & 7) * CPX + (lin >> 3);    // bijective (3328 = 8*416)
    const int jt   = tile & 3;
    const int rest = tile >> 2;                       // 0..831 = 32*26
    const int it   = rest % NBAND;
    const int b    = rest / NBAND;
    const int i0 = min(TH * it, HO - TH);   // clamped (edge tiles duplicate compute)
    const int j0 = min(TW * jt, WO - TW);

    const float4* xbase = reinterpret_cast<const float4*>(
        x + (((size_t)b * HH + (size_t)i0) * WW + (size_t)j0) * CIN);   // row stride 2048

    // ---- stage: issue global loads, then convert + swizzled LDS write ----
    float4 va[STAGE_ITERS], vb[STAGE_ITERS];
#pragma unroll
    for (int t = 0; t < STAGE_ITERS; ++t) {
        const int f = min(tid + t * 256, LDS_CHUNKS - 1);
        const int row = f / ROWCH, rem = f - row * ROWCH;
        va[t] = xbase[(size_t)row * 2048 + 2 * rem];
        vb[t] = xbase[(size_t)row * 2048 + 2 * rem + 1];
    }
#pragma unroll
    for (int t = 0; t < STAGE_ITERS; ++t) {
        const int f = tid + t * 256;
        if (f < LDS_CHUNKS) {
            const int row = f / ROWCH, rem = f - row * ROWCH;
            const int px = rem >> 2, gg = rem & 3;
            ldsH[row * ROWCH + (px << 2) + (gg ^ (px & 3))] = pack_pkrtz(va[t], vb[t]);
        }
    }

    const int lane = tid & 63;
    const int m = lane & 15, g = lane >> 4;

    // ---- W-fragments resident (18 x 4 VGPR) ----
    const half8* wbp = reinterpret_cast<const half8*>(wb);
    half8 Bf[18];
#pragma unroll
    for (int q = 0; q < 18; ++q) Bf[q] = wbp[q * 64 + lane];

    // ---- epilogue constants (pre-barrier, overlaps staging latency) ----
    const float res = residual[0];
    const float4 kc4 = reinterpret_cast<const float4*>(Kc)[g & 1];
    half8 a2;                                // cb^T frag: row o=m, k-row r=g*8+e
#pragma unroll
    for (int e = 0; e < 8; ++e) {
        const int r = g * 8 + e;
        const float w = cb[min(r, 8) * OO + m];
        a2[e] = (_Float16)((r <= 8) ? w : 0.f);
    }
    unsigned resw;
    { unsigned short rb = f2h(res); resw = (unsigned)rb; }  // fp16 res, low half

    __syncthreads();                        // all 12 rows visible; ONE barrier total

    const int wv_ = tid >> 6;

    // per-lane chunk offset per kj (nt adds nt*64): pixel p = m+kj
    int bc[3];
#pragma unroll
    for (int kj = 0; kj < 3; ++kj) {
        const int p = m + kj;
        bc[kj] = (p << 2) + (g ^ (p & 3));
    }

    auto compute_row = [&](int row0) {
        f32x4 acc[4];
#pragma unroll
        for (int nt = 0; nt < 4; ++nt) acc[nt] = (f32x4){0.f, 0.f, 0.f, 0.f};

        const half8* baseS = ldsH + row0 * ROWCH;
#pragma unroll
        for (int ki = 0; ki < 3; ++ki) {
#pragma unroll
            for (int kj = 0; kj < 3; ++kj) {
                const int tap = ki * 3 + kj;
                half8 ax[4];
#pragma unroll
                for (int nt = 0; nt < 4; ++nt)
                    ax[nt] = baseS[ki * ROWCH + nt * 64 + bc[kj]];
#pragma unroll
                for (int nt = 0; nt < 4; ++nt)   // D1 = W·X
                    acc[nt] = __builtin_amdgcn_mfma_f32_16x16x32_f16(Bf[2 * tap], ax[nt], acc[nt], 0, 0, 0);
#pragma unroll
                for (int nt = 0; nt < 4; ++nt) {
                    const half8 ax2 = ax[nt] * ax[nt];       // v_pk_mul_f16
                    acc[nt] = __builtin_amdgcn_mfma_f32_16x16x32_f16(Bf[2 * tap + 1], ax2, acc[nt], 0, 0, 0);
                }
            }
        }

        // ---- in-register epilogue per 16-pixel tile ----
        const size_t orow = ((size_t)b * HO + (size_t)(i0 + row0)) * WO + (size_t)j0;
#pragma unroll
        for (int nt = 0; nt < 4; ++nt) {
            float phv[4];
#pragma unroll
            for (int e = 0; e < 4; ++e) {
                const float t = __expf(acc[nt][e] + ((const float*)&kc4)[e]);
                phv[e] = (g < 2) ? t : 0.f;
            }
            const float S = (phv[0] + phv[1]) + (phv[2] + phv[3]);
            const float T = S + __shfl_xor(S, 16);
            const float denom = T + __shfl_xor(T, 32) + res + 1e-9f;
            const float inv = __builtin_amdgcn_rcpf(denom);

            const unsigned w01 = (unsigned)f2h(phv[0]) | ((unsigned)f2h(phv[1]) << 16);
            const unsigned w23 = (unsigned)f2h(phv[2]) | ((unsigned)f2h(phv[3]) << 16);
            const unsigned p01 = __shfl_xor(w01, 16);
            const unsigned p23 = __shfl_xor(w23, 16);
            uint4 bw;
            bw.x = (g == 0) ? w01 : ((g == 1) ? resw : 0u);   // g1 k-row 8 = residual
            bw.y = (g == 0) ? w23 : 0u;
            bw.z = (g == 0) ? p01 : 0u;
            bw.w = (g == 0) ? p23 : 0u;
            const half8 b2 = __builtin_bit_cast(half8, bw);

            f32x4 acc2 = (f32x4){0.f, 0.f, 0.f, 0.f};
            acc2 = __builtin_amdgcn_mfma_f32_16x16x32_f16(a2, b2, acc2, 0, 0, 0);

            f32x4 v;
            v[0] = acc2[0] * inv; v[1] = acc2[1] * inv;
            v[2] = acc2[2] * inv; v[3] = acc2[3] * inv;
            float* op = out + (orow + (size_t)(nt * 16 + m)) * OO + g * 4;
            __builtin_nontemporal_store(v, reinterpret_cast<f32x4*>(op));
        }
    };

    compute_row(wv_);                       // rows i0..i0+3
    compute_row(4 + wv_);                   // rows i0+4..i0+7
    if (wv_ < 2) compute_row(8 + wv_);      // rows i0+8..i0+9
}

extern "C" void kernel_launch(void* const* d_in, const int* in_sizes, int n_in,
                              void* d_out, int out_size, void* d_ws, size_t ws_size,
                              hipStream_t stream) {
    const float* x     = (const float*)d_in[0];
    const float* sigma = (const float*)d_in[1];   // (3,3,32,8)
    const float* mu    = (const float*)d_in[2];   // (8,32)
    const float* resid = (const float*)d_in[3];   // (1,)
    const float* cb    = (const float*)d_in[4];   // (9,16)
    float* outp = (float*)d_out;

    float* Kc = (float*)d_ws;                          // 8 floats
    unsigned short* wb = (unsigned short*)(Kc + 8);    // 18*64*8 fp16 = 18432 B

    hipLaunchKernelGGL(prep_kernel, dim3(1), dim3(256), 0, stream, sigma, mu, wb, Kc);
    hipLaunchKernelGGL(fuzzy_main, dim3(NTILE), dim3(256), 0, stream,
                       x, wb, Kc, resid, cb, outp);
}

// Round 14
// 86.109 us; speedup vs baseline: 1.0446x; 1.0446x over previous
//
#include <hip/hip_runtime.h>

// fuzzyConv: B=32, H=W=256, C=32, R=8, O=16, 3x3 VALID -> H'=W'=254
// BEST-MEASURED VARIANT (R8, 86.3 µs) restored after the structural search:
// R5 persistent=131, R9 split=104, R12 deferred=89.4, R13 TH10=89.9,
// R11 TH7/4blk=86.6 -- all levers (occupancy, fetch volume, redundancy,
// pipelining) null; kernel streams at ~5.4 TB/s combined CU-side, ~86% of
// the 6.3 TB/s copy ceiling.
//
// Premise as implicit GEMM on matrix cores (fp16 features, fp32 accum),
// OPERAND-SWAPPED: D1[rule,pixel] = W·X so the epilogue needs no transpose.
//   exponent_r(p) = sum_{tap,c} [ (s2*mu)*x + (-0.5*s2)*x^2 ] + K_r
// TH=8 tile (10 staged rows, 42240 B LDS -> 3 blocks/CU), chunked XCD
// swizzle. Single stage + ONE barrier. cvt_pkrtz packed fp32->fp16.
// In-register epilogue (exp, shfl denom, second MFMA out = cb^T·phi_aug),
// nontemporal float4 stores.

#define CIN 32
#define HH  256
#define WW  256
#define HO  254
#define WO  254
#define BB  32
#define OO  16

#define TW 64
#define TH 8
#define LROWS 10                    // TH+2 staged input rows
#define LPIX 66                     // TW+2 staged pixels per row
#define ROWCH (LPIX * 4)            // 264 16-B chunks per row (8 fp16 ch each)
#define LDS_CHUNKS (LROWS * ROWCH)  // 2640 chunks = 42240 B
#define STAGE_ITERS 11              // ceil(2640/256)
#define NTILE (4 * 32 * BB)         // 4096 blocks

typedef _Float16 half8 __attribute__((ext_vector_type(8)));   // 8 fp16 (4 VGPR)
typedef float f32x4 __attribute__((ext_vector_type(4)));

static __device__ __forceinline__ unsigned short f2h(float f) {
    _Float16 h = (_Float16)f;
    return *reinterpret_cast<unsigned short*>(&h);
}

static __device__ __forceinline__ half8 pack_pkrtz(const float4& a, const float4& b) {
    uint4 u;
    u.x = __builtin_bit_cast(unsigned, __builtin_amdgcn_cvt_pkrtz(a.x, a.y));
    u.y = __builtin_bit_cast(unsigned, __builtin_amdgcn_cvt_pkrtz(a.z, a.w));
    u.z = __builtin_bit_cast(unsigned, __builtin_amdgcn_cvt_pkrtz(b.x, b.y));
    u.w = __builtin_bit_cast(unsigned, __builtin_amdgcn_cvt_pkrtz(b.z, b.w));
    return __builtin_bit_cast(half8, u);
}

// ---------------- prep: W-fragments (fp16) + K constants ----------------
// wb: 18 frags = tap(9) x ftype(2); ftype0 pairs with x (w = s2*mu),
// ftype1 pairs with x^2 (w = -0.5*s2). A-operand layout: lane l -> row
// m=l&15 = rule (0-pad >=8), k-element e -> channel c = (l>>4)*8+e.
__global__ __launch_bounds__(256) void prep_kernel(const float* __restrict__ sigma,
                                                   const float* __restrict__ mu,
                                                   unsigned short* __restrict__ wb,
                                                   float* __restrict__ Kc) {
    const int tid = threadIdx.x;
    for (int item = tid; item < 18 * 64; item += 256) {
        const int frag = item >> 6;          // 0..17
        const int lane = item & 63;
        const int tap = frag >> 1, ftype = frag & 1;
        const int n = lane & 15, g = lane >> 4;
#pragma unroll
        for (int e = 0; e < 8; ++e) {
            float wgt = 0.f;
            if (n < 8) {
                const int c = g * 8 + e;
                const float sg = sigma[(tap * CIN + c) * 8 + n];   // (3,3,C,R)
                const float s2 = sg * sg;
                wgt = ftype ? -0.5f * s2 : s2 * mu[n * CIN + c];
            }
            wb[item * 8 + e] = f2h(wgt);
        }
    }
    if (tid < 8) {
        const int r = tid;
        float k = 0.f;
        for (int item = 0; item < 9 * CIN; ++item) {
            const int c = item & 31;
            const float sg = sigma[item * 8 + r];
            const float m = mu[r * CIN + c];
            k = fmaf(sg * sg, m * m, k);
        }
        Kc[r] = -0.5f * k;
    }
}

// ---------------- main kernel ----------------
// Block 256 = 4 waves; wave w owns output rows (i0+w) and (i0+w+4);
// 64 px = 4 N-tiles of 16. LDS: 10 rows x 66 px x 32ch fp16, swizzled.
__global__ __launch_bounds__(256, 3) void fuzzy_main(const float* __restrict__ x,
                                                     const unsigned short* __restrict__ wb,
                                                     const float* __restrict__ Kc,
                                                     const float* __restrict__ residual,
                                                     const float* __restrict__ cb,
                                                     float* __restrict__ out) {
    __shared__ __align__(16) unsigned char ldsRaw[LDS_CHUNKS * 16];   // 42240 B
    half8* ldsH = reinterpret_cast<half8*>(ldsRaw);

    const int tid = threadIdx.x;
    // chunked XCD swizzle: XCD k gets a contiguous band of tiles ordered
    // (b, it, jt)-major -> vertical halo neighbors on the same XCD L2.
    const int lin  = blockIdx.x;
    const int tile = ((lin & 7) << 9) | (lin >> 3);   // 4096 = 8 * 512, bijective
    const int jt = tile & 3;
    const int it = (tile >> 2) & 31;
    const int b  = tile >> 7;
    const int i0 = min(TH * it, HO - TH);   // clamped (edge tiles duplicate compute)
    const int j0 = min(TW * jt, WO - TW);

    const float4* xbase = reinterpret_cast<const float4*>(
        x + (((size_t)b * HH + (size_t)i0) * WW + (size_t)j0) * CIN);   // row stride 2048

    // ---- stage: issue global loads, then convert + swizzled LDS write ----
    float4 va[STAGE_ITERS], vb[STAGE_ITERS];
#pragma unroll
    for (int t = 0; t < STAGE_ITERS; ++t) {
        const int f = min(tid + t * 256, LDS_CHUNKS - 1);
        const int row = f / ROWCH, rem = f - row * ROWCH;
        va[t] = xbase[(size_t)row * 2048 + 2 * rem];
        vb[t] = xbase[(size_t)row * 2048 + 2 * rem + 1];
    }
#pragma unroll
    for (int t = 0; t < STAGE_ITERS; ++t) {
        const int f = tid + t * 256;
        if (f < LDS_CHUNKS) {
            const int row = f / ROWCH, rem = f - row * ROWCH;
            const int px = rem >> 2, gg = rem & 3;
            ldsH[row * ROWCH + (px << 2) + (gg ^ (px & 3))] = pack_pkrtz(va[t], vb[t]);
        }
    }

    const int lane = tid & 63;
    const int m = lane & 15, g = lane >> 4;

    // ---- W-fragments resident (18 x 4 VGPR) ----
    const half8* wbp = reinterpret_cast<const half8*>(wb);
    half8 Bf[18];
#pragma unroll
    for (int q = 0; q < 18; ++q) Bf[q] = wbp[q * 64 + lane];

    // ---- epilogue constants (pre-barrier, overlaps staging latency) ----
    const float res = residual[0];
    const float4 kc4 = reinterpret_cast<const float4*>(Kc)[g & 1];
    half8 a2;                                // cb^T frag: row o=m, k-row r=g*8+e
#pragma unroll
    for (int e = 0; e < 8; ++e) {
        const int r = g * 8 + e;
        const float w = cb[min(r, 8) * OO + m];
        a2[e] = (_Float16)((r <= 8) ? w : 0.f);
    }
    unsigned resw;
    { unsigned short rb = f2h(res); resw = (unsigned)rb; }  // fp16 res, low half

    __syncthreads();                        // all 10 rows visible; ONE barrier total

    const int wv_ = tid >> 6;

    // per-lane chunk offset per kj (nt adds nt*64): pixel p = m+kj
    int bc[3];
#pragma unroll
    for (int kj = 0; kj < 3; ++kj) {
        const int p = m + kj;
        bc[kj] = (p << 2) + (g ^ (p & 3));
    }

#pragma unroll
    for (int half = 0; half < 2; ++half) {
        const int row0 = wv_ + 4 * half;     // staged-row base for this output row

        f32x4 acc[4];
#pragma unroll
        for (int nt = 0; nt < 4; ++nt) acc[nt] = (f32x4){0.f, 0.f, 0.f, 0.f};

        const half8* baseS = ldsH + row0 * ROWCH;
#pragma unroll
        for (int ki = 0; ki < 3; ++ki) {
#pragma unroll
            for (int kj = 0; kj < 3; ++kj) {
                const int tap = ki * 3 + kj;
                half8 ax[4];
#pragma unroll
                for (int nt = 0; nt < 4; ++nt)
                    ax[nt] = baseS[ki * ROWCH + nt * 64 + bc[kj]];
#pragma unroll
                for (int nt = 0; nt < 4; ++nt)   // D1 = W·X
                    acc[nt] = __builtin_amdgcn_mfma_f32_16x16x32_f16(Bf[2 * tap], ax[nt], acc[nt], 0, 0, 0);
#pragma unroll
                for (int nt = 0; nt < 4; ++nt) {
                    const half8 ax2 = ax[nt] * ax[nt];       // v_pk_mul_f16
                    acc[nt] = __builtin_amdgcn_mfma_f32_16x16x32_f16(Bf[2 * tap + 1], ax2, acc[nt], 0, 0, 0);
                }
            }
        }

        // ---- in-register epilogue per 16-pixel tile ----
        const size_t orow = ((size_t)b * HO + (size_t)(i0 + row0)) * WO + (size_t)j0;
#pragma unroll
        for (int nt = 0; nt < 4; ++nt) {
            float phv[4];
#pragma unroll
            for (int e = 0; e < 4; ++e) {
                const float t = __expf(acc[nt][e] + ((const float*)&kc4)[e]);
                phv[e] = (g < 2) ? t : 0.f;
            }
            const float S = (phv[0] + phv[1]) + (phv[2] + phv[3]);
            const float T = S + __shfl_xor(S, 16);
            const float denom = T + __shfl_xor(T, 32) + res + 1e-9f;
            const float inv = __builtin_amdgcn_rcpf(denom);

            const unsigned w01 = (unsigned)f2h(phv[0]) | ((unsigned)f2h(phv[1]) << 16);
            const unsigned w23 = (unsigned)f2h(phv[2]) | ((unsigned)f2h(phv[3]) << 16);
            const unsigned p01 = __shfl_xor(w01, 16);
            const unsigned p23 = __shfl_xor(w23, 16);
            uint4 bw;
            bw.x = (g == 0) ? w01 : ((g == 1) ? resw : 0u);   // g1 k-row 8 = residual
            bw.y = (g == 0) ? w23 : 0u;
            bw.z = (g == 0) ? p01 : 0u;
            bw.w = (g == 0) ? p23 : 0u;
            const half8 b2 = __builtin_bit_cast(half8, bw);

            f32x4 acc2 = (f32x4){0.f, 0.f, 0.f, 0.f};
            acc2 = __builtin_amdgcn_mfma_f32_16x16x32_f16(a2, b2, acc2, 0, 0, 0);

            f32x4 v;
            v[0] = acc2[0] * inv; v[1] = acc2[1] * inv;
            v[2] = acc2[2] * inv; v[3] = acc2[3] * inv;
            float* op = out + (orow + (size_t)(nt * 16 + m)) * OO + g * 4;
            __builtin_nontemporal_store(v, reinterpret_cast<f32x4*>(op));
        }
    }
}

extern "C" void kernel_launch(void* const* d_in, const int* in_sizes, int n_in,
                              void* d_out, int out_size, void* d_ws, size_t ws_size,
                              hipStream_t stream) {
    const float* x     = (const float*)d_in[0];
    const float* sigma = (const float*)d_in[1];   // (3,3,32,8)
    const float* mu    = (const float*)d_in[2];   // (8,32)
    const float* resid = (const float*)d_in[3];   // (1,)
    const float* cb    = (const float*)d_in[4];   // (9,16)
    float* outp = (float*)d_out;

    float* Kc = (float*)d_ws;                          // 8 floats
    unsigned short* wb = (unsigned short*)(Kc + 8);    // 18*64*8 fp16 = 18432 B

    hipLaunchKernelGGL(prep_kernel, dim3(1), dim3(256), 0, stream, sigma, mu, wb, Kc);
    hipLaunchKernelGGL(fuzzy_main, dim3(NTILE), dim3(256), 0, stream,
                       x, wb, Kc, resid, cb, outp);
}